// Round 4
// baseline (354.037 us; speedup 1.0000x reference)
//
#include <hip/hip_runtime.h>

typedef float f32x4 __attribute__((ext_vector_type(4)));

// ---------------- minifloat quantize (e4m3-style: E=4, M=3, bias=7) ----------------
// grid: emin=-6, emax=7, max=240. floor(log2|t|) == fp32 exponent field (normals);
// zeros/denormals fall into the clamped-subnormal path and round to 0 exactly as ref.
// VALIDATED round 3: absmax 0.0 vs np reference.
__device__ __forceinline__ float quant1(float t) {
    unsigned bits = __float_as_uint(t);
    int eb = (int)((bits & 0x7fffffffu) >> 23);   // biased exponent of |t|
    eb = eb < 121 ? 121 : eb;                     // clamp: e >= -6  (121 = -6+127)
    float m = __uint_as_float((unsigned)(257 - eb) << 23);  // 2^(3-e)
    float s = __uint_as_float((unsigned)(eb - 3) << 23);    // 2^(e-3)
    float q = rintf(t * m) * s;                   // RNE, matches np.round
    q = fminf(q, 240.0f);
    q = fmaxf(q, -240.0f);
    return q;
}

// Exact e4m3fn (OCP) encode of a value ALREADY on the minifloat grid.
// All grid values (|v| in {0} U [2^-9, 240]) are representable; no rounding occurs.
__device__ __forceinline__ unsigned fp8q1(float t) {
    float q = quant1(t);
    unsigned qb = __float_as_uint(q);
    unsigned sg = (qb >> 24) & 0x80u;             // sign -> bit 7
    unsigned aq = qb & 0x7fffffffu;
    unsigned e2 = aq >> 23;                        // fp32 biased exponent of |q|
    // subnormal (|q| = k*2^-9, k=1..7): byte = k   (exact: |q|*512 == k)
    unsigned sub = (unsigned)(int)(__uint_as_float(aq) * 512.0f);
    // normal (e >= -6): e4m3 exp = e2-120 in [1,14], mantissa = top 3 bits
    unsigned nrm = ((e2 - 120u) << 3) | ((qb >> 20) & 7u);
    unsigned mag = (aq == 0u) ? 0u : (e2 >= 121u ? nrm : sub);
    return sg | mag;
}

// ---------------- fused quantize kernel: x then w, fp8 out, grid-stride -------------
__global__ void quant8_fp8_kernel(const float* __restrict__ x, const float* __restrict__ w,
                                  unsigned char* __restrict__ xq, unsigned char* __restrict__ wq,
                                  long long n8x, long long n8tot) {
    long long stride = (long long)gridDim.x * blockDim.x;
    for (long long c = (long long)blockIdx.x * blockDim.x + threadIdx.x;
         c < n8tot; c += stride) {
        const float4* src;
        unsigned char* dst;
        long long i;
        if (c < n8x) { src = (const float4*)x; dst = xq; i = c; }
        else         { src = (const float4*)w; dst = wq; i = c - n8x; }
        float4 a = src[2 * i], b = src[2 * i + 1];
        unsigned lo = fp8q1(a.x) | (fp8q1(a.y) << 8) | (fp8q1(a.z) << 16) | (fp8q1(a.w) << 24);
        unsigned hi = fp8q1(b.x) | (fp8q1(b.y) << 8) | (fp8q1(b.z) << 16) | (fp8q1(b.w) << 24);
        uint2 o; o.x = lo; o.y = hi;
        ((uint2*)dst)[i] = o;
    }
}

// ---------------- fp8 MFMA GEMM: C[M,N] = A[M,K] * B[N,K]^T + quant(bias) -----------
// Same proven 2-phase structure as round 3 (byte-identical staging geometry:
// 128 rows x 64 B per tile), but fp8 elements -> BK=64, 32 MFMA per K-tile,
// half the K-loop iterations and half the staged bytes per K-element.
#define BM 128
#define BN 128
#define BKF 64   /* fp8 elements per K-tile (64 B rows, same as bf16 BK=32) */

__device__ __forceinline__ void gload_lds16(const void* g, void* l) {
    __builtin_amdgcn_global_load_lds(
        (const __attribute__((address_space(1))) void*)g,
        (__attribute__((address_space(3))) void*)l, 16, 0, 0);
}

__global__ __launch_bounds__(256, 2) void gemm_fp8q_kernel(
    const unsigned char* __restrict__ A,   // [M,K] fp8 e4m3fn
    const unsigned char* __restrict__ B,   // [N,K] fp8 e4m3fn (w layout)
    const float* __restrict__ bias,        // [N] raw fp32 bias (quantized here)
    float* __restrict__ C, int M, int N, int K)
{
    __shared__ __align__(16) unsigned char As[BM * BKF];  // 8 KB
    __shared__ __align__(16) unsigned char Bs[BN * BKF];  // 8 KB

    const int t    = threadIdx.x;
    const int lane = t & 63;
    const int wid  = t >> 6;           // 4 waves: 2x2
    const int wm   = (wid >> 1) * 64;  // wave row offset in tile
    const int wn   = (wid & 1) * 64;   // wave col offset in tile
    const int fr   = lane & 15;        // fragment row/col index
    const int kg   = lane >> 4;        // k-group 0..3 (8 fp8 each)

    const int rowA0 = blockIdx.x * BM;
    const int colB0 = blockIdx.y * BN;

    f32x4 acc[4][4] = {};

    const int c0 = t;          // staging chunk ids (16B each, 512 chunks per tile)
    const int c1 = t + 256;
    const int r0 = c0 >> 2, j0 = (c0 & 3) * 16;
    const int r1 = c1 >> 2, j1 = (c1 & 3) * 16;

    for (int kt = 0; kt < K; kt += BKF) {
        // ---- stage A & B tiles: global -> LDS, 16B per lane, wave-linear dest ----
        gload_lds16(A + (size_t)(rowA0 + r0) * K + kt + j0, &As[c0 * 16]);
        gload_lds16(A + (size_t)(rowA0 + r1) * K + kt + j1, &As[c1 * 16]);
        gload_lds16(B + (size_t)(colB0 + r0) * K + kt + j0, &Bs[c0 * 16]);
        gload_lds16(B + (size_t)(colB0 + r1) * K + kt + j1, &Bs[c1 * 16]);
        __syncthreads();   // compiler drains vmcnt before barrier

        long af[4][2], bf[4][2];
        #pragma unroll
        for (int m = 0; m < 4; ++m)
            #pragma unroll
            for (int s = 0; s < 2; ++s)
                af[m][s] = *(const long*)&As[(wm + m * 16 + fr) * BKF + s * 32 + kg * 8];
        #pragma unroll
        for (int n = 0; n < 4; ++n)
            #pragma unroll
            for (int s = 0; s < 2; ++s)
                bf[n][s] = *(const long*)&Bs[(wn + n * 16 + fr) * BKF + s * 32 + kg * 8];

        #pragma unroll
        for (int m = 0; m < 4; ++m)
            #pragma unroll
            for (int n = 0; n < 4; ++n)
                #pragma unroll
                for (int s = 0; s < 2; ++s)
                    acc[m][n] = __builtin_amdgcn_mfma_f32_16x16x32_fp8_fp8(
                        af[m][s], bf[n][s], acc[m][n], 0, 0, 0);

        __syncthreads();
    }

    // ---- epilogue: C/D layout col=lane&15, row=(lane>>4)*4+reg (validated) ----
    #pragma unroll
    for (int m = 0; m < 4; ++m) {
        int row = rowA0 + wm + m * 16 + kg * 4;
        #pragma unroll
        for (int n = 0; n < 4; ++n) {
            int col = colB0 + wn + n * 16 + fr;
            float bb = quant1(bias[col]);
            #pragma unroll
            for (int r = 0; r < 4; ++r)
                C[(size_t)(row + r) * N + col] = acc[m][n][r] + bb;
        }
    }
}

// ---------------- naive fallback (no workspace needed) ----------------
__global__ void naive_gemm_kernel(const float* __restrict__ x, const float* __restrict__ w,
                                  const float* __restrict__ b, float* __restrict__ out,
                                  int M, int N, int K) {
    int col = blockIdx.x * blockDim.x + threadIdx.x;
    int row = blockIdx.y;
    if (col >= N || row >= M) return;
    const float* xr = x + (size_t)row * K;
    const float* wr = w + (size_t)col * K;
    float acc = 0.f;
    for (int k = 0; k < K; ++k) acc += quant1(xr[k]) * quant1(wr[k]);
    out[(size_t)row * N + col] = acc + quant1(b[col]);
}

extern "C" void kernel_launch(void* const* d_in, const int* in_sizes, int n_in,
                              void* d_out, int out_size, void* d_ws, size_t ws_size,
                              hipStream_t stream) {
    const float* x = (const float*)d_in[0];
    const float* w = (const float*)d_in[1];
    const float* b = (const float*)d_in[2];
    float* out = (float*)d_out;

    const int xsz = in_sizes[0];
    const int wsz = in_sizes[1];
    const int N   = in_sizes[2];
    const int K   = wsz / N;
    const int M   = xsz / K;

    const size_t xq_bytes = (size_t)xsz;          // fp8: 1 B/elem
    const size_t need = xq_bytes + (size_t)wsz;

    const bool fast_ok = (ws_size >= need) &&
                         (M % BM == 0) && (N % BN == 0) && (K % BKF == 0) &&
                         (xsz % 8 == 0) && (wsz % 8 == 0);

    if (fast_ok) {
        unsigned char* xq = (unsigned char*)d_ws;
        unsigned char* wq = (unsigned char*)d_ws + xq_bytes;

        long long n8x = xsz / 8;
        long long n8tot = n8x + wsz / 8;
        quant8_fp8_kernel<<<2048, 256, 0, stream>>>(x, w, xq, wq, n8x, n8tot);

        dim3 grid(M / BM, N / BN);
        gemm_fp8q_kernel<<<grid, 256, 0, stream>>>(xq, wq, b, out, M, N, K);
    } else {
        dim3 grid((N + 255) / 256, M);
        naive_gemm_kernel<<<grid, 256, 0, stream>>>(x, w, b, out, M, N, K);
    }
}

// Round 5
// 284.277 us; speedup vs baseline: 1.2454x; 1.2454x over previous
//
#include <hip/hip_runtime.h>

typedef float f32x4 __attribute__((ext_vector_type(4)));
typedef long  i64x2 __attribute__((ext_vector_type(2)));

// ---------------- minifloat quantize (e4m3-style: E=4, M=3, bias=7) ----------------
// VALIDATED round 3: absmax 0.0 vs np reference. Used for bias + naive fallback.
__device__ __forceinline__ float quant1(float t) {
    unsigned bits = __float_as_uint(t);
    int eb = (int)((bits & 0x7fffffffu) >> 23);
    eb = eb < 121 ? 121 : eb;                     // clamp: e >= -6
    float m = __uint_as_float((unsigned)(257 - eb) << 23);  // 2^(3-e)
    float s = __uint_as_float((unsigned)(eb - 3) << 23);    // 2^(e-3)
    float q = rintf(t * m) * s;                   // RNE, matches np.round
    q = fminf(q, 240.0f);
    q = fmaxf(q, -240.0f);
    return q;
}

// Direct minifloat -> OCP e4m3fn encode. Same grid as quant1 (RNE to 3-bit
// mantissa via carry-propagating add; ties-to-even via +lsb; subnormal path
// |t|*512 RNE gives k=0..8 where k=8 == byte 0x08 == 2^-6 exactly).
__device__ __forceinline__ unsigned fp8enc(float t) {
    unsigned b  = __float_as_uint(t);
    unsigned sg = (b >> 24) & 0x80u;
    unsigned a  = b & 0x7fffffffu;
    unsigned mag;
    if (a < 0x3C800000u) {                          // |t| < 2^-6: subnormal grid
        mag = (unsigned)(int)rintf(__uint_as_float(a) * 512.0f);
    } else {
        mag = ((a + 0x7FFFFu + ((a >> 20) & 1u)) >> 20) - 0x3C0u;
        mag = mag > 0x77u ? 0x77u : mag;            // saturate at 240
    }
    return sg | mag;
}

// ------------- fused quantize + tile/swizzle kernel (x then w) ----------------------
// Output layout: per 128-row block blk, per K-tile kt (64 fp8), an 8192 B tile.
// Chunk c in [0,512): 16 B = row r=c>>2, slot kgpos=c&3. Logical k-bytes for this
// slot: kg = kgpos ^ ((r>>1)&3); bytes = enc(in[row, kt*64 + kg*8 + {0..7}]) then
// enc(in[row, kt*64 + 32 + kg*8 + {0..7}]).  (XOR pre-swizzle kills LDS read
// bank conflicts; GEMM reads b128 at row*64 + kgpos*16.)
__global__ void quant_tile_fp8_kernel(const float* __restrict__ x, const float* __restrict__ w,
                                      unsigned char* __restrict__ xq, unsigned char* __restrict__ wq,
                                      long long nAc, long long nTot, int K, int ktlog) {
    const long long stride = (long long)gridDim.x * blockDim.x;
    const int nktm1 = (1 << ktlog) - 1;
    for (long long chunk = (long long)blockIdx.x * blockDim.x + threadIdx.x;
         chunk < nTot; chunk += stride) {
        const bool isA = chunk < nAc;
        const float* src = isA ? x : w;
        unsigned char* dst = isA ? xq : wq;
        const long long cc = isA ? chunk : chunk - nAc;
        const long long tile = cc >> 9;
        const int c = (int)(cc & 511);
        const int r = c >> 2, kgpos = c & 3;
        const int kg = kgpos ^ ((r >> 1) & 3);
        const long long blk = tile >> ktlog;
        const int kt0 = (int)(tile & nktm1);
        const float* s0 = src + (blk * 128 + r) * (long long)K + kt0 * 64 + kg * 8;
        float4 a0 = *(const float4*)(s0);
        float4 a1 = *(const float4*)(s0 + 4);
        float4 b0 = *(const float4*)(s0 + 32);
        float4 b1 = *(const float4*)(s0 + 36);
        uint4 o;
        o.x = fp8enc(a0.x) | (fp8enc(a0.y) << 8) | (fp8enc(a0.z) << 16) | (fp8enc(a0.w) << 24);
        o.y = fp8enc(a1.x) | (fp8enc(a1.y) << 8) | (fp8enc(a1.z) << 16) | (fp8enc(a1.w) << 24);
        o.z = fp8enc(b0.x) | (fp8enc(b0.y) << 8) | (fp8enc(b0.z) << 16) | (fp8enc(b0.w) << 24);
        o.w = fp8enc(b1.x) | (fp8enc(b1.y) << 8) | (fp8enc(b1.z) << 16) | (fp8enc(b1.w) << 24);
        ((uint4*)dst)[cc] = o;   // linear: cc*16 == tile*8192 + c*16
    }
}

// ---------------- fp8 MFMA GEMM on pre-tiled operands ------------------------------
#define BM 128
#define BN 128
#define BKB 64   /* fp8 per K-tile */

__device__ __forceinline__ void gload_lds16(const void* g, void* l) {
    __builtin_amdgcn_global_load_lds(
        (const __attribute__((address_space(1))) void*)g,
        (__attribute__((address_space(3))) void*)l, 16, 0, 0);
}

__global__ __launch_bounds__(256, 2) void gemm_fp8t_kernel(
    const unsigned char* __restrict__ At,  // [M/128][K/64][8192] pre-swizzled
    const unsigned char* __restrict__ Bt,  // [N/128][K/64][8192] pre-swizzled
    const float* __restrict__ bias,        // raw fp32, quantized in epilogue
    float* __restrict__ C, int M, int N, int K)
{
    __shared__ __align__(16) unsigned char As[BM * BKB];  // 8 KB
    __shared__ __align__(16) unsigned char Bs[BN * BKB];  // 8 KB

    const int t    = threadIdx.x;
    const int lane = t & 63;
    const int wid  = t >> 6;           // 4 waves: 2x2
    const int wm   = (wid >> 1) * 64;
    const int wn   = (wid & 1) * 64;
    const int fr   = lane & 15;
    const int kg   = lane >> 4;

    const int nkt = K / BKB;
    const unsigned char* pA = At + (size_t)blockIdx.x * nkt * 8192;
    const unsigned char* pB = Bt + (size_t)blockIdx.y * nkt * 8192;

    // hoisted per-lane LDS read offsets: one b128 per fragment (both K-slices)
    int offA[4], offB[4];
    #pragma unroll
    for (int m = 0; m < 4; ++m) {
        int row = wm + m * 16 + fr;
        offA[m] = row * 64 + ((kg ^ ((row >> 1) & 3)) << 4);
    }
    #pragma unroll
    for (int n = 0; n < 4; ++n) {
        int row = wn + n * 16 + fr;
        offB[n] = row * 64 + ((kg ^ ((row >> 1) & 3)) << 4);
    }

    f32x4 acc[4][4] = {};

    for (int kt = 0; kt < nkt; ++kt) {
        // ---- stage: purely linear global -> LDS (tile bytes ARE the LDS image) ----
        gload_lds16(pA + t * 16,        &As[t * 16]);
        gload_lds16(pA + t * 16 + 4096, &As[t * 16 + 4096]);
        gload_lds16(pB + t * 16,        &Bs[t * 16]);
        gload_lds16(pB + t * 16 + 4096, &Bs[t * 16 + 4096]);
        pA += 8192; pB += 8192;
        __syncthreads();   // compiler drains vmcnt before barrier

        i64x2 av[4], bv[4];
        #pragma unroll
        for (int m = 0; m < 4; ++m) av[m] = *(const i64x2*)&As[offA[m]];
        #pragma unroll
        for (int n = 0; n < 4; ++n) bv[n] = *(const i64x2*)&Bs[offB[n]];

        #pragma unroll
        for (int m = 0; m < 4; ++m)
            #pragma unroll
            for (int n = 0; n < 4; ++n) {
                acc[m][n] = __builtin_amdgcn_mfma_f32_16x16x32_fp8_fp8(
                    av[m][0], bv[n][0], acc[m][n], 0, 0, 0);
                acc[m][n] = __builtin_amdgcn_mfma_f32_16x16x32_fp8_fp8(
                    av[m][1], bv[n][1], acc[m][n], 0, 0, 0);
            }

        __syncthreads();
    }

    // ---- epilogue: C/D layout col=lane&15, row=(lane>>4)*4+reg (validated) ----
    #pragma unroll
    for (int m = 0; m < 4; ++m) {
        int row = blockIdx.x * BM + wm + m * 16 + kg * 4;
        #pragma unroll
        for (int n = 0; n < 4; ++n) {
            int col = blockIdx.y * BN + wn + n * 16 + fr;
            float bb = quant1(bias[col]);
            #pragma unroll
            for (int r = 0; r < 4; ++r)
                C[(size_t)(row + r) * N + col] = acc[m][n][r] + bb;
        }
    }
}

// ---------------- naive fallback (no workspace needed) ----------------
__global__ void naive_gemm_kernel(const float* __restrict__ x, const float* __restrict__ w,
                                  const float* __restrict__ b, float* __restrict__ out,
                                  int M, int N, int K) {
    int col = blockIdx.x * blockDim.x + threadIdx.x;
    int row = blockIdx.y;
    if (col >= N || row >= M) return;
    const float* xr = x + (size_t)row * K;
    const float* wr = w + (size_t)col * K;
    float acc = 0.f;
    for (int k = 0; k < K; ++k) acc += quant1(xr[k]) * quant1(wr[k]);
    out[(size_t)row * N + col] = acc + quant1(b[col]);
}

extern "C" void kernel_launch(void* const* d_in, const int* in_sizes, int n_in,
                              void* d_out, int out_size, void* d_ws, size_t ws_size,
                              hipStream_t stream) {
    const float* x = (const float*)d_in[0];
    const float* w = (const float*)d_in[1];
    const float* b = (const float*)d_in[2];
    float* out = (float*)d_out;

    const int xsz = in_sizes[0];
    const int wsz = in_sizes[1];
    const int N   = in_sizes[2];
    const int K   = wsz / N;
    const int M   = xsz / K;

    const size_t need = (size_t)xsz + (size_t)wsz;   // fp8: 1 B/elem
    const int nkt = K / BKB;
    const bool nkt_pow2 = nkt > 0 && (nkt & (nkt - 1)) == 0;

    const bool fast_ok = (ws_size >= need) && nkt_pow2 &&
                         (M % BM == 0) && (N % BN == 0) && (K % BKB == 0);

    if (fast_ok) {
        unsigned char* xq = (unsigned char*)d_ws;
        unsigned char* wq = (unsigned char*)d_ws + xsz;

        int ktlog = 0;
        while ((1 << ktlog) < nkt) ++ktlog;

        const long long nAc = (long long)xsz / 16;
        const long long nTot = nAc + (long long)wsz / 16;
        quant_tile_fp8_kernel<<<2048, 256, 0, stream>>>(x, w, xq, wq, nAc, nTot, K, ktlog);

        dim3 grid(M / BM, N / BN);
        gemm_fp8t_kernel<<<grid, 256, 0, stream>>>(xq, wq, b, out, M, N, K);
    } else {
        dim3 grid((N + 255) / 256, M);
        naive_gemm_kernel<<<grid, 256, 0, stream>>>(x, w, b, out, M, N, K);
    }
}

// Round 8
// 279.304 us; speedup vs baseline: 1.2676x; 1.0178x over previous
//
#include <hip/hip_runtime.h>

typedef float f32x16 __attribute__((ext_vector_type(16)));
typedef int   i32x8  __attribute__((ext_vector_type(8)));

// ---------------- minifloat quantize (e4m3-style: E=4, M=3, bias=7) ----------------
// VALIDATED round 3: absmax 0.0 vs np reference. Used for bias + naive fallback.
__device__ __forceinline__ float quant1(float t) {
    unsigned bits = __float_as_uint(t);
    int eb = (int)((bits & 0x7fffffffu) >> 23);
    eb = eb < 121 ? 121 : eb;                     // clamp: e >= -6
    float m = __uint_as_float((unsigned)(257 - eb) << 23);  // 2^(3-e)
    float s = __uint_as_float((unsigned)(eb - 3) << 23);    // 2^(e-3)
    float q = rintf(t * m) * s;                   // RNE, matches np.round
    q = fminf(q, 240.0f);
    q = fmaxf(q, -240.0f);
    return q;
}

// Direct minifloat -> OCP e4m3fn encode. VALIDATED rounds 4-6 (absmax 0.0156 =
// pure accumulation-order noise on first launch). RNE via carry-propagating add
// (+lsb for ties-to-even); subnormal path |t|*512 RNE -> k=0..8 (k=8 == 0x08 == 2^-6).
__device__ __forceinline__ unsigned fp8enc(float t) {
    unsigned b  = __float_as_uint(t);
    unsigned sg = (b >> 24) & 0x80u;
    unsigned a  = b & 0x7fffffffu;
    unsigned mag;
    if (a < 0x3C800000u) {                          // |t| < 2^-6: subnormal grid
        mag = (unsigned)(int)rintf(__uint_as_float(a) * 512.0f);
    } else {
        mag = ((a + 0x7FFFFu + ((a >> 20) & 1u)) >> 20) - 0x3C0u;
        mag = mag > 0x77u ? 0x77u : mag;            // saturate at 240
    }
    return sg | mag;
}

// ------------- fused quantize + tile/swizzle kernel (x then w) ----------------------
// Output: per 128-row block, per K-tile (64 fp8), an 8192 B tile that IS the LDS
// image. Chunk c in [0,512): 16 B at row r=c>>2, physical slot p=c&3 holding
// logical k-slot s = p ^ ((r>>1)&3)  (XOR kills LDS read bank conflicts; staging
// stays linear for global_load_lds — both-sides-or-neither discipline).
__global__ void quant_tile_fp8_kernel(const float* __restrict__ x, const float* __restrict__ w,
                                      unsigned char* __restrict__ xq, unsigned char* __restrict__ wq,
                                      long long nAc, long long nTot, int K, int ktlog) {
    const long long stride = (long long)gridDim.x * blockDim.x;
    const int nktm1 = (1 << ktlog) - 1;
    for (long long chunk = (long long)blockIdx.x * blockDim.x + threadIdx.x;
         chunk < nTot; chunk += stride) {
        const bool isA = chunk < nAc;
        const float* src = isA ? x : w;
        unsigned char* dst = isA ? xq : wq;
        const long long cc = isA ? chunk : chunk - nAc;
        const long long tile = cc >> 9;
        const int c = (int)(cc & 511);
        const int r = c >> 2, p = c & 3;
        const int s = p ^ ((r >> 1) & 3);
        const long long blk = tile >> ktlog;
        const int kt0 = (int)(tile & nktm1);
        const float* s0 = src + (blk * 128 + r) * (long long)K + kt0 * 64 + s * 16;
        float4 a0 = *(const float4*)(s0);
        float4 a1 = *(const float4*)(s0 + 4);
        float4 b0 = *(const float4*)(s0 + 8);
        float4 b1 = *(const float4*)(s0 + 12);
        uint4 o;
        o.x = fp8enc(a0.x) | (fp8enc(a0.y) << 8) | (fp8enc(a0.z) << 16) | (fp8enc(a0.w) << 24);
        o.y = fp8enc(a1.x) | (fp8enc(a1.y) << 8) | (fp8enc(a1.z) << 16) | (fp8enc(a1.w) << 24);
        o.z = fp8enc(b0.x) | (fp8enc(b0.y) << 8) | (fp8enc(b0.z) << 16) | (fp8enc(b0.w) << 24);
        o.w = fp8enc(b1.x) | (fp8enc(b1.y) << 8) | (fp8enc(b1.z) << 16) | (fp8enc(b1.w) << 24);
        ((uint4*)dst)[cc] = o;   // linear: cc*16 == tile*8192 + c*16
    }
}

// --------- MX-scaled fp8 MFMA GEMM (unit scales): 2x rate vs fp8_fp8 [m148] ---------
#define BM 128
#define BN 128
#define BKB 64   /* fp8 per K-tile */

__device__ __forceinline__ void gload_lds16(const void* g, void* l) {
    __builtin_amdgcn_global_load_lds(
        (const __attribute__((address_space(1))) void*)g,
        (__attribute__((address_space(3))) void*)l, 16, 0, 0);
}

__global__ __launch_bounds__(256, 2) void gemm_fp8s_kernel(
    const unsigned char* __restrict__ At,  // [M/128][K/64][8192] pre-swizzled
    const unsigned char* __restrict__ Bt,  // [N/128][K/64][8192] pre-swizzled
    const float* __restrict__ bias,        // raw fp32, quantized in epilogue
    float* __restrict__ C, int M, int N, int K)
{
    __shared__ __align__(16) unsigned char As[BM * BKB];  // 8 KB
    __shared__ __align__(16) unsigned char Bs[BN * BKB];  // 8 KB

    const int t    = threadIdx.x;
    const int lane = t & 63;
    const int wid  = t >> 6;           // 4 waves: 2x2, each owns a 64x64 subtile
    const int wm   = (wid >> 1) * 64;
    const int wn   = (wid & 1) * 64;
    const int l31  = lane & 31;        // fragment row/col
    const int hi2  = lane >> 5;        // k-group 0..1 (32 fp8 each)

    const int nkt = K / BKB;
    const unsigned char* pA = At + (size_t)blockIdx.x * nkt * 8192;
    const unsigned char* pB = Bt + (size_t)blockIdx.y * nkt * 8192;

    // per-lane LDS byte offsets of logical slot s=2*hi2 for each 32x32 fragment;
    // the partner slot (s+1) lives at offset^16 (slots are XOR-permuted pairs)
    int offA[2], offB[2];
    #pragma unroll
    for (int mi = 0; mi < 2; ++mi) {
        int row = wm + mi * 32 + l31;
        offA[mi] = row * 64 + ((((hi2 << 1)) ^ ((row >> 1) & 3)) << 4);
    }
    #pragma unroll
    for (int ni = 0; ni < 2; ++ni) {
        int row = wn + ni * 32 + l31;
        offB[ni] = row * 64 + ((((hi2 << 1)) ^ ((row >> 1) & 3)) << 4);
    }

    f32x16 acc[2][2] = {};

    for (int kt = 0; kt < nkt; ++kt) {
        // ---- stage: purely linear global -> LDS (tile bytes ARE the LDS image) ----
        gload_lds16(pA + t * 16,        &As[t * 16]);
        gload_lds16(pA + t * 16 + 4096, &As[t * 16 + 4096]);
        gload_lds16(pB + t * 16,        &Bs[t * 16]);
        gload_lds16(pB + t * 16 + 4096, &Bs[t * 16 + 4096]);
        pA += 8192; pB += 8192;

        // HARDENING (r6 post-timing divergence): force the global_load_lds drain
        // ourselves instead of relying on the compiler's pre-barrier waitcnt.
        asm volatile("s_waitcnt vmcnt(0)" ::: "memory");
        __builtin_amdgcn_sched_barrier(0);
        __syncthreads();

        i32x8 av[2], bv[2];
        #pragma unroll
        for (int mi = 0; mi < 2; ++mi) {
            uint4 lo = *(const uint4*)&As[offA[mi]];
            uint4 hi = *(const uint4*)&As[offA[mi] ^ 16];
            i32x8 v; v[0]=(int)lo.x; v[1]=(int)lo.y; v[2]=(int)lo.z; v[3]=(int)lo.w;
                     v[4]=(int)hi.x; v[5]=(int)hi.y; v[6]=(int)hi.z; v[7]=(int)hi.w;
            av[mi] = v;
        }
        #pragma unroll
        for (int ni = 0; ni < 2; ++ni) {
            uint4 lo = *(const uint4*)&Bs[offB[ni]];
            uint4 hi = *(const uint4*)&Bs[offB[ni] ^ 16];
            i32x8 v; v[0]=(int)lo.x; v[1]=(int)lo.y; v[2]=(int)lo.z; v[3]=(int)lo.w;
                     v[4]=(int)hi.x; v[5]=(int)hi.y; v[6]=(int)hi.z; v[7]=(int)hi.w;
            bv[ni] = v;
        }

        #pragma unroll
        for (int mi = 0; mi < 2; ++mi)
            #pragma unroll
            for (int ni = 0; ni < 2; ++ni)
                // cbsz=0 (A fp8 e4m3), blgp=0 (B fp8 e4m3), scales 127 = E8M0 1.0
                acc[mi][ni] = __builtin_amdgcn_mfma_scale_f32_32x32x64_f8f6f4(
                    av[mi], bv[ni], acc[mi][ni], 0, 0, 0, 127, 0, 127);

        __syncthreads();
    }

    // ---- epilogue: 32x32 C/D layout col=lane&31, row=(reg&3)+8*(reg>>2)+4*(lane>>5)
    #pragma unroll
    for (int mi = 0; mi < 2; ++mi) {
        int row0 = blockIdx.x * BM + wm + mi * 32 + hi2 * 4;
        #pragma unroll
        for (int ni = 0; ni < 2; ++ni) {
            int col = blockIdx.y * BN + wn + ni * 32 + l31;
            float bb = quant1(bias[col]);
            #pragma unroll
            for (int reg = 0; reg < 16; ++reg) {
                int row = row0 + (reg & 3) + 8 * (reg >> 2);
                C[(size_t)row * N + col] = acc[mi][ni][reg] + bb;
            }
        }
    }
}

// ---------------- naive fallback (no workspace needed) ----------------
__global__ void naive_gemm_kernel(const float* __restrict__ x, const float* __restrict__ w,
                                  const float* __restrict__ b, float* __restrict__ out,
                                  int M, int N, int K) {
    int col = blockIdx.x * blockDim.x + threadIdx.x;
    int row = blockIdx.y;
    if (col >= N || row >= M) return;
    const float* xr = x + (size_t)row * K;
    const float* wr = w + (size_t)col * K;
    float acc = 0.f;
    for (int k = 0; k < K; ++k) acc += quant1(xr[k]) * quant1(wr[k]);
    out[(size_t)row * N + col] = acc + quant1(b[col]);
}

extern "C" void kernel_launch(void* const* d_in, const int* in_sizes, int n_in,
                              void* d_out, int out_size, void* d_ws, size_t ws_size,
                              hipStream_t stream) {
    const float* x = (const float*)d_in[0];
    const float* w = (const float*)d_in[1];
    const float* b = (const float*)d_in[2];
    float* out = (float*)d_out;

    const int xsz = in_sizes[0];
    const int wsz = in_sizes[1];
    const int N   = in_sizes[2];
    const int K   = wsz / N;
    const int M   = xsz / K;

    const size_t need = (size_t)xsz + (size_t)wsz;   // fp8: 1 B/elem
    const int nkt = K / BKB;
    const bool nkt_pow2 = nkt > 0 && (nkt & (nkt - 1)) == 0;

    const bool fast_ok = (ws_size >= need) && nkt_pow2 &&
                         (M % BM == 0) && (N % BN == 0) && (K % BKB == 0);

    if (fast_ok) {
        unsigned char* xq = (unsigned char*)d_ws;
        unsigned char* wq = (unsigned char*)d_ws + xsz;

        int ktlog = 0;
        while ((1 << ktlog) < nkt) ++ktlog;

        const long long nAc = (long long)xsz / 16;
        const long long nTot = nAc + (long long)wsz / 16;
        quant_tile_fp8_kernel<<<2048, 256, 0, stream>>>(x, w, xq, wq, nAc, nTot, K, ktlog);

        dim3 grid(M / BM, N / BN);
        gemm_fp8s_kernel<<<grid, 256, 0, stream>>>(xq, wq, b, out, M, N, K);
    } else {
        dim3 grid((N + 255) / 256, M);
        naive_gemm_kernel<<<grid, 256, 0, stream>>>(x, w, b, out, M, N, K);
    }
}